// Round 8
// baseline (159.142 us; speedup 1.0000x reference)
//
#include <hip/hip_runtime.h>
#include <hip/hip_bf16.h>

#define IN_F 4096
#define OUT_F 11008
#define TOKENS 32
#define RANK 16
#define KSPLIT 8
#define KSLICE (IN_F / KSPLIT)  // 512
#define XPAD 520                // u16 per LDS x-row (512 data + 8 pad)
#define OUT_ELEMS (TOKENS * OUT_F)  // 352256
#define NGEMM (86 * KSPLIT)     // 688 GEMM blocks

typedef unsigned short u16;
typedef __attribute__((ext_vector_type(8))) short bf16x8;
typedef __attribute__((ext_vector_type(4))) float f32x4;
typedef __attribute__((ext_vector_type(4))) int i32x4;

__device__ const float NF4_d[16] = {
    -1.0f, -0.6961928009986877f, -0.5250730514526367f, -0.39491748809814453f,
    -0.28444138169288635f, -0.18477343022823334f, -0.09105003625154495f, 0.0f,
    0.07958029955625534f, 0.16093020141124725f, 0.24611230194568634f,
    0.33791524171829224f, 0.44070982933044434f, 0.5626170039176941f,
    0.7229568362236023f, 1.0f};

static __device__ __forceinline__ unsigned pk2(float a, float b) {
    __hip_bfloat162 h = __float22bfloat162_rn(make_float2(a, b));
    unsigned u;
    __builtin_memcpy(&u, &h, 4);
    return u;
}

// kernel 1: blocks [0,688) = NF4-dequant MFMA GEMM partials -> ws (plain stores);
//           blocks [688,1200) = xa[t][r] = x[t]·A[r]  (fully independent work)
__global__ __launch_bounds__(256, 4) void qlora_part_xa(
    const int* __restrict__ packed, const float* __restrict__ scales,
    const float* __restrict__ x, const float* __restrict__ A,
    float* __restrict__ part, float* __restrict__ xa) {
    __shared__ u16 xs[32 * XPAD];  // 32 tokens x 512 k (bf16), padded rows
    __shared__ unsigned tbl[256];  // byte -> packed bf16 (hi16=hi, lo16=lo)
    const int tid = threadIdx.x;

    if (blockIdx.x >= NGEMM) {  // ---- xa path ----
        int b = blockIdx.x - NGEMM;  // 0..511
        int t = b >> 4, r = b & 15;
        const float4* xr = (const float4*)(x + t * IN_F);
        const float4* ar = (const float4*)(A + r * IN_F);
        float s = 0.f;
        for (int c = 0; c < 4; ++c) {
            int j = c * 256 + tid;
            float4 xv = xr[j], av = ar[j];
            s += xv.x * av.x + xv.y * av.y + xv.z * av.z + xv.w * av.w;
        }
        for (int off = 32; off > 0; off >>= 1) s += __shfl_down(s, off, 64);
        __shared__ float w4[4];
        if ((tid & 63) == 0) w4[tid >> 6] = s;
        __syncthreads();
        if (tid == 0) xa[b] = w4[0] + w4[1] + w4[2] + w4[3];
        return;
    }

    // ---- GEMM path (R7 tile, unchanged except stores) ----
    const int bx = blockIdx.x % 86;
    const int by = blockIdx.x / 86;
    const int kbase = by * KSLICE;

    const int lane = tid & 63;
    const int wv = tid >> 6;
    const int n = lane & 15;
    const int q = lane >> 4;
    const int olo = bx * 128 + wv * 32 + n;
    const int ohi = olo + 16;

    const i32x4* pp0 = (const i32x4*)(packed + olo * 2048 + (kbase >> 1)) + q;
    const i32x4* pp1 = (const i32x4*)(packed + ohi * 2048 + (kbase >> 1)) + q;
    i32x4 P0[2], P1[2];
    P0[0] = __builtin_nontemporal_load(pp0);
    P1[0] = __builtin_nontemporal_load(pp1);
    P0[1] = __builtin_nontemporal_load(pp0 + 4);
    P1[1] = __builtin_nontemporal_load(pp1 + 4);

    const float4* sp0 = (const float4*)(scales + olo * 64 + (kbase >> 6));
    const float4* sp1 = (const float4*)(scales + ohi * 64 + (kbase >> 6));
    float4 s0A = sp0[0], s0B = sp0[1];
    float4 s1A = sp1[0], s1B = sp1[1];

    tbl[tid] = pk2(NF4_d[tid & 15], NF4_d[tid >> 4]);

    for (int it = 0; it < 8; ++it) {
        int row = it * 4 + (tid >> 6);
        int c8 = tid & 63;
        const float4* src = (const float4*)(x + row * IN_F + kbase + c8 * 8);
        float4 v0 = src[0], v1 = src[1];
        uint4 d;
        d.x = pk2(v0.x, v0.y);
        d.y = pk2(v0.z, v0.w);
        d.z = pk2(v1.x, v1.y);
        d.w = pk2(v1.z, v1.w);
        *(uint4*)(xs + row * XPAD + c8 * 8) = d;
    }
    __syncthreads();

    f32x4 acc00 = {0.f, 0.f, 0.f, 0.f};
    f32x4 acc10 = {0.f, 0.f, 0.f, 0.f};
    f32x4 acc01 = {0.f, 0.f, 0.f, 0.f};
    f32x4 acc11 = {0.f, 0.f, 0.f, 0.f};
    const u16* xr0 = xs + n * XPAD + q * 8;
    const u16* xr1 = xs + (n + 16) * XPAD + q * 8;
    const float sc0r[8] = {s0A.x, s0A.y, s0A.z, s0A.w, s0B.x, s0B.y, s0B.z, s0B.w};
    const float sc1r[8] = {s1A.x, s1A.y, s1A.z, s1A.w, s1B.x, s1B.y, s1B.z, s1B.w};

#pragma unroll
    for (int s = 0; s < 16; ++s) {
        i32x4 c0 = P0[s & 1];
        i32x4 c1 = P1[s & 1];
        if (s + 2 < 16) {
            P0[s & 1] = __builtin_nontemporal_load(pp0 + (s + 2) * 4);
            P1[s & 1] = __builtin_nontemporal_load(pp1 + (s + 2) * 4);
        }
        float sc0 = sc0r[s >> 1];
        float sc1 = sc1r[s >> 1];

        uint4 b0u, b1u;
        {
            unsigned u0 = tbl[c0[0] & 255], u1 = tbl[c0[1] & 255];
            unsigned u2 = tbl[c0[2] & 255], u3 = tbl[c0[3] & 255];
            b0u.x = pk2(__int_as_float(u0 & 0xFFFF0000u) * sc0, __int_as_float(u0 << 16) * sc0);
            b0u.y = pk2(__int_as_float(u1 & 0xFFFF0000u) * sc0, __int_as_float(u1 << 16) * sc0);
            b0u.z = pk2(__int_as_float(u2 & 0xFFFF0000u) * sc0, __int_as_float(u2 << 16) * sc0);
            b0u.w = pk2(__int_as_float(u3 & 0xFFFF0000u) * sc0, __int_as_float(u3 << 16) * sc0);
        }
        {
            unsigned u0 = tbl[c1[0] & 255], u1 = tbl[c1[1] & 255];
            unsigned u2 = tbl[c1[2] & 255], u3 = tbl[c1[3] & 255];
            b1u.x = pk2(__int_as_float(u0 & 0xFFFF0000u) * sc1, __int_as_float(u0 << 16) * sc1);
            b1u.y = pk2(__int_as_float(u1 & 0xFFFF0000u) * sc1, __int_as_float(u1 << 16) * sc1);
            b1u.z = pk2(__int_as_float(u2 & 0xFFFF0000u) * sc1, __int_as_float(u2 << 16) * sc1);
            b1u.w = pk2(__int_as_float(u3 & 0xFFFF0000u) * sc1, __int_as_float(u3 << 16) * sc1);
        }
        bf16x8 bf0, bf1;
        __builtin_memcpy(&bf0, &b0u, 16);
        __builtin_memcpy(&bf1, &b1u, 16);
        bf16x8 a0 = *(const bf16x8*)(xr0 + s * 32);
        bf16x8 a1 = *(const bf16x8*)(xr1 + s * 32);
        acc00 = __builtin_amdgcn_mfma_f32_16x16x32_bf16(a0, bf0, acc00, 0, 0, 0);
        acc10 = __builtin_amdgcn_mfma_f32_16x16x32_bf16(a1, bf0, acc10, 0, 0, 0);
        acc01 = __builtin_amdgcn_mfma_f32_16x16x32_bf16(a0, bf1, acc01, 0, 0, 0);
        acc11 = __builtin_amdgcn_mfma_f32_16x16x32_bf16(a1, bf1, acc11, 0, 0, 0);
    }

    // partials -> ws (plain nontemporal stores; no zero-init, no atomics)
    float* pb = part + by * OUT_ELEMS;
#pragma unroll
    for (int r = 0; r < 4; ++r) {
        int t = q * 4 + r;
        __builtin_nontemporal_store(acc00[r], pb + t * OUT_F + olo);
        __builtin_nontemporal_store(acc10[r], pb + (t + 16) * OUT_F + olo);
        __builtin_nontemporal_store(acc01[r], pb + t * OUT_F + ohi);
        __builtin_nontemporal_store(acc11[r], pb + (t + 16) * OUT_F + ohi);
    }
}

// kernel 2: out = sum of 8 partials + xa @ B^T   (float4 per thread)
__global__ void reduce_lora(const float* __restrict__ part,
                            const float* __restrict__ xa,
                            const float* __restrict__ B,
                            float* __restrict__ out) {
    int idx4 = blockIdx.x * 256 + threadIdx.x;  // 88064 total
    int t = idx4 / (OUT_F / 4);
    int o4 = idx4 - t * (OUT_F / 4);
    int base = t * OUT_F + o4 * 4;

    float4 s = *(const float4*)(part + base);
#pragma unroll
    for (int y = 1; y < KSPLIT; ++y) {
        float4 p = *(const float4*)(part + y * OUT_ELEMS + base);
        s.x += p.x;
        s.y += p.y;
        s.z += p.z;
        s.w += p.w;
    }

    const float4* xt = (const float4*)(xa + t * RANK);
    float4 x0 = xt[0], x1 = xt[1], x2 = xt[2], x3 = xt[3];
    const float4* br = (const float4*)(B + o4 * 4 * RANK);
    float res[4];
#pragma unroll
    for (int j = 0; j < 4; ++j) {
        float4 b0 = br[j * 4 + 0], b1 = br[j * 4 + 1];
        float4 b2 = br[j * 4 + 2], b3 = br[j * 4 + 3];
        res[j] = b0.x * x0.x + b0.y * x0.y + b0.z * x0.z + b0.w * x0.w +
                 b1.x * x1.x + b1.y * x1.y + b1.z * x1.z + b1.w * x1.w +
                 b2.x * x2.x + b2.y * x2.y + b2.z * x2.z + b2.w * x2.w +
                 b3.x * x3.x + b3.y * x3.y + b3.z * x3.z + b3.w * x3.w;
    }
    s.x += res[0];
    s.y += res[1];
    s.z += res[2];
    s.w += res[3];
    *(float4*)(out + base) = s;  // SCALING = 1.0
}

extern "C" void kernel_launch(void* const* d_in, const int* in_sizes, int n_in,
                              void* d_out, int out_size, void* d_ws, size_t ws_size,
                              hipStream_t stream) {
    const float* x = (const float*)d_in[0];
    const int* packed = (const int*)d_in[1];
    const float* scales = (const float*)d_in[2];
    const float* lora_A = (const float*)d_in[3];
    const float* lora_B = (const float*)d_in[4];
    float* out = (float*)d_out;

    float* part = (float*)d_ws;                                   // 8 x 1.409 MB
    float* xa = (float*)((char*)d_ws + KSPLIT * OUT_ELEMS * 4);   // 2048 B

    qlora_part_xa<<<NGEMM + 512, 256, 0, stream>>>(packed, scales, x, lora_A, part, xa);
    reduce_lora<<<(TOKENS * OUT_F / 4) / 256, 256, 0, stream>>>(part, xa, lora_B, out);
}

// Round 9
// 153.325 us; speedup vs baseline: 1.0379x; 1.0379x over previous
//
#include <hip/hip_runtime.h>
#include <hip/hip_bf16.h>

#define IN_F 4096
#define OUT_F 11008
#define TOKENS 32
#define RANK 16
#define KSPLIT 8
#define KSLICE (IN_F / KSPLIT)  // 512
#define XPAD 520                // u16 per LDS x-row (512 data + 8 pad)
#define OUT_ELEMS (TOKENS * OUT_F)  // 352256

typedef unsigned short u16;
typedef __attribute__((ext_vector_type(8))) short bf16x8;
typedef __attribute__((ext_vector_type(4))) float f32x4;
typedef __attribute__((ext_vector_type(4))) int i32x4;

__device__ const float NF4_d[16] = {
    -1.0f, -0.6961928009986877f, -0.5250730514526367f, -0.39491748809814453f,
    -0.28444138169288635f, -0.18477343022823334f, -0.09105003625154495f, 0.0f,
    0.07958029955625534f, 0.16093020141124725f, 0.24611230194568634f,
    0.33791524171829224f, 0.44070982933044434f, 0.5626170039176941f,
    0.7229568362236023f, 1.0f};

static __device__ __forceinline__ unsigned pk2(float a, float b) {
    __hip_bfloat162 h = __float22bfloat162_rn(make_float2(a, b));
    unsigned u;
    __builtin_memcpy(&u, &h, 4);
    return u;
}

// kernel 1: blocks 0..511 compute xa[t][r]; blocks 512..575 zero out[]
__global__ void prep_xa_zero(const float* __restrict__ x, const float* __restrict__ A,
                             float* __restrict__ xa, float* __restrict__ out) {
    __shared__ float red[256];
    if (blockIdx.x >= 512) {
        int i = (blockIdx.x - 512) * 256 + threadIdx.x;  // 16384 threads
        float4 z = make_float4(0.f, 0.f, 0.f, 0.f);
        for (int j = i; j < OUT_ELEMS / 4; j += 16384) ((float4*)out)[j] = z;
        return;
    }
    int b = blockIdx.x;  // 0..511
    int t = b >> 4, r = b & 15;
    const float4* xr = (const float4*)(x + t * IN_F);
    const float4* ar = (const float4*)(A + r * IN_F);
    float s = 0.f;
    for (int c = 0; c < 4; ++c) {
        int j = c * 256 + threadIdx.x;
        float4 xv = xr[j], av = ar[j];
        s += xv.x * av.x + xv.y * av.y + xv.z * av.z + xv.w * av.w;
    }
    red[threadIdx.x] = s;
    __syncthreads();
    for (int st = 128; st > 0; st >>= 1) {
        if (threadIdx.x < st) red[threadIdx.x] += red[threadIdx.x + st];
        __syncthreads();
    }
    if (threadIdx.x == 0) xa[b] = red[0];
}

// kernel 2: NF4 dequant + bf16 MFMA GEMM + fused lora epilogue (y==0 slice)
__global__ __launch_bounds__(256, 4) void qlora_fused(
    const int* __restrict__ packed, const float* __restrict__ scales,
    const float* __restrict__ x, const float* __restrict__ xa,
    const float* __restrict__ B, float* __restrict__ out) {
    __shared__ u16 xs[32 * XPAD];  // 32 tokens x 512 k (bf16), padded rows
    __shared__ unsigned tbl[256];  // byte -> packed bf16 (hi16=hi_code, lo16=lo_code)
    __shared__ float xal[512];     // xa staged (used by y==0 blocks only)
    const int tid = threadIdx.x;
    const int kbase = blockIdx.y * KSLICE;
    const int obase = blockIdx.x * 64;

    const int lane = tid & 63;
    const int wv = tid >> 6;
    const int n = lane & 15;  // output col within wave tile
    const int q = lane >> 4;  // k-subblock
    const int o = obase + wv * 16 + n;

    // deep packed prefetch FIRST (nontemporal: 90 MB single-use stream)
    const i32x4* ppq = (const i32x4*)(packed + o * 2048 + (kbase >> 1)) + q;
    i32x4 P[4];
    P[0] = __builtin_nontemporal_load(ppq);
    P[1] = __builtin_nontemporal_load(ppq + 4);
    P[2] = __builtin_nontemporal_load(ppq + 8);
    P[3] = __builtin_nontemporal_load(ppq + 12);

    // per-lane group scales (8 floats, 32B contiguous) into registers
    const float4* sp = (const float4*)(scales + o * 64 + (kbase >> 6));
    float4 sA = sp[0], sB = sp[1];

    // dequant table: hi16 = bf16(hi-nibble code), lo16 = bf16(lo-nibble code)
    tbl[tid] = pk2(NF4_d[tid & 15], NF4_d[tid >> 4]);

    if (blockIdx.y == 0) {  // stage xa for lora epilogue
        xal[tid] = xa[tid];
        xal[tid + 256] = xa[tid + 256];
    }

    // stage x slice: 32 rows x 512, fp32 -> bf16 during staging
    for (int it = 0; it < 8; ++it) {
        int row = it * 4 + (tid >> 6);
        int c8 = tid & 63;
        const float4* src = (const float4*)(x + row * IN_F + kbase + c8 * 8);
        float4 v0 = src[0], v1 = src[1];
        uint4 d;
        d.x = pk2(v0.x, v0.y);
        d.y = pk2(v0.z, v0.w);
        d.z = pk2(v1.x, v1.y);
        d.w = pk2(v1.z, v1.w);
        *(uint4*)(xs + row * XPAD + c8 * 8) = d;
    }
    __syncthreads();

    f32x4 acc0 = {0.f, 0.f, 0.f, 0.f};
    f32x4 acc1 = {0.f, 0.f, 0.f, 0.f};
    const u16* xr0 = xs + n * XPAD + q * 8;
    const u16* xr1 = xs + (n + 16) * XPAD + q * 8;
    const float scr[8] = {sA.x, sA.y, sA.z, sA.w, sB.x, sB.y, sB.z, sB.w};

#pragma unroll
    for (int s = 0; s < 16; ++s) {
        i32x4 cur = P[s & 3];
        if (s + 4 < 16) P[s & 3] = __builtin_nontemporal_load(ppq + (s + 4) * 4);
        float sc = scr[s >> 1];  // compile-time select (fully unrolled)

        unsigned u0 = tbl[cur[0] & 255];
        unsigned u1 = tbl[cur[1] & 255];
        unsigned u2 = tbl[cur[2] & 255];
        unsigned u3 = tbl[cur[3] & 255];
        uint4 bu;
        bu.x = pk2(__int_as_float(u0 & 0xFFFF0000u) * sc, __int_as_float(u0 << 16) * sc);
        bu.y = pk2(__int_as_float(u1 & 0xFFFF0000u) * sc, __int_as_float(u1 << 16) * sc);
        bu.z = pk2(__int_as_float(u2 & 0xFFFF0000u) * sc, __int_as_float(u2 << 16) * sc);
        bu.w = pk2(__int_as_float(u3 & 0xFFFF0000u) * sc, __int_as_float(u3 << 16) * sc);
        bf16x8 bfrag;
        __builtin_memcpy(&bfrag, &bu, 16);
        bf16x8 a0 = *(const bf16x8*)(xr0 + s * 32);
        bf16x8 a1 = *(const bf16x8*)(xr1 + s * 32);
        acc0 = __builtin_amdgcn_mfma_f32_16x16x32_bf16(a0, bfrag, acc0, 0, 0, 0);
        acc1 = __builtin_amdgcn_mfma_f32_16x16x32_bf16(a1, bfrag, acc1, 0, 0, 0);
    }

    // fused lora term (only the y==0 K-slice adds it)
    float lora[8] = {0.f, 0.f, 0.f, 0.f, 0.f, 0.f, 0.f, 0.f};
    if (blockIdx.y == 0) {
        const float4* br = (const float4*)(B + o * RANK);
        float4 b0 = br[0], b1 = br[1], b2 = br[2], b3 = br[3];
#pragma unroll
        for (int r = 0; r < 4; ++r) {
            const float* x0 = xal + (q * 4 + r) * RANK;
            const float* x1 = xal + (q * 4 + r + 16) * RANK;
            float s0, s1;
            s0 = b0.x * x0[0] + b0.y * x0[1] + b0.z * x0[2] + b0.w * x0[3] +
                 b1.x * x0[4] + b1.y * x0[5] + b1.z * x0[6] + b1.w * x0[7] +
                 b2.x * x0[8] + b2.y * x0[9] + b2.z * x0[10] + b2.w * x0[11] +
                 b3.x * x0[12] + b3.y * x0[13] + b3.z * x0[14] + b3.w * x0[15];
            s1 = b0.x * x1[0] + b0.y * x1[1] + b0.z * x1[2] + b0.w * x1[3] +
                 b1.x * x1[4] + b1.y * x1[5] + b1.z * x1[6] + b1.w * x1[7] +
                 b2.x * x1[8] + b2.y * x1[9] + b2.z * x1[10] + b2.w * x1[11] +
                 b3.x * x1[12] + b3.y * x1[13] + b3.z * x1[14] + b3.w * x1[15];
            lora[r] = s0;
            lora[r + 4] = s1;
        }
    }

    // C/D layout: col = lane&15 (o), row = (lane>>4)*4 + reg (token)
#pragma unroll
    for (int r = 0; r < 4; ++r) {
        int t = q * 4 + r;
        atomicAdd(out + t * OUT_F + o, acc0[r] + lora[r]);
        atomicAdd(out + (t + 16) * OUT_F + o, acc1[r] + lora[r + 4]);
    }
}

extern "C" void kernel_launch(void* const* d_in, const int* in_sizes, int n_in,
                              void* d_out, int out_size, void* d_ws, size_t ws_size,
                              hipStream_t stream) {
    const float* x = (const float*)d_in[0];
    const int* packed = (const int*)d_in[1];
    const float* scales = (const float*)d_in[2];
    const float* lora_A = (const float*)d_in[3];
    const float* lora_B = (const float*)d_in[4];
    float* out = (float*)d_out;

    float* xa = (float*)d_ws;  // 2048 B

    prep_xa_zero<<<576, 256, 0, stream>>>(x, lora_A, xa, out);
    qlora_fused<<<dim3(OUT_F / 64, KSPLIT), 256, 0, stream>>>(packed, scales, x, xa,
                                                              lora_B, out);
}